// Round 6
// baseline (295.970 us; speedup 1.0000x reference)
//
#include <hip/hip_runtime.h>

// ---------------- problem constants ----------------
// B=4, S=2048, D=1024, H=16, HD=64; M = B*S = 8192
#define SB 4
#define SS 2048
#define SD 1024
#define SH 16
#define SHD 64
#define SM (SB * SS)   // 8192

typedef __bf16 bf16x8 __attribute__((ext_vector_type(8)));
typedef float f32x4 __attribute__((ext_vector_type(4)));

static __device__ __forceinline__ unsigned short f2bf(float x) {
    unsigned int u = __builtin_bit_cast(unsigned int, x);
    u += 0x7fffu + ((u >> 16) & 1u);   // RNE (no NaNs in this problem)
    return (unsigned short)(u >> 16);
}

static __device__ __forceinline__ float fast_exp2(float x) {
#if __has_builtin(__builtin_amdgcn_exp2f)
    return __builtin_amdgcn_exp2f(x);
#else
    return exp2f(x);
#endif
}

// pack high16(a)<<16 | high16(b) via v_perm_b32 (bf16 truncation, 1 inst / 2 vals)
static __device__ __forceinline__ unsigned int pkhi(float a, float b) {
    return __builtin_amdgcn_perm(__builtin_bit_cast(unsigned int, a),
                                 __builtin_bit_cast(unsigned int, b), 0x07060302u);
}

typedef __attribute__((address_space(1))) void GV;
typedef __attribute__((address_space(3))) void LV;

static __device__ __forceinline__ void async16(const void* g, void* l) {
    __builtin_amdgcn_global_load_lds((GV*)g, (LV*)l, 16, 0, 0);
}

// Q pre-scale: 1/sqrt(64) * log2(e) -> softmax runs natively in log2 domain
#define QSCALE 0.18033688011112042f

// ---------------- fused cast fp32 -> bf16 (x, wq, wk, wv, wo in one launch) ----
__global__ __launch_bounds__(256) void cast_all(
    const float* __restrict__ x,  const float* __restrict__ wq,
    const float* __restrict__ wk, const float* __restrict__ wv,
    const float* __restrict__ wo,
    unsigned short* __restrict__ xb, unsigned short* __restrict__ wqkv,
    unsigned short* __restrict__ wo16) {
    int i = blockIdx.x * 256 + threadIdx.x;
    const float4* src;
    ushort4* dst;
    if (i < 2097152) {
        src = reinterpret_cast<const float4*>(x) + i;
        dst = reinterpret_cast<ushort4*>(xb) + i;
    } else {
        int j = i - 2097152;
        int which = j >> 18;          // 262144 float4 per weight
        int r = j & 262143;
        const float* ws_[4] = {wq, wk, wv, wo};
        src = reinterpret_cast<const float4*>(ws_[which]) + r;
        dst = (which < 3 ? reinterpret_cast<ushort4*>(wqkv) + which * 262144
                         : reinterpret_cast<ushort4*>(wo16)) + r;
    }
    float4 v = *src;
    ushort4 o;
    o.x = f2bf(v.x); o.y = f2bf(v.y); o.z = f2bf(v.z); o.w = f2bf(v.w);
    *dst = o;
}

// ---------------- 128x128 GEMM mainloop v2 ----------------
// Double-buffered (one barrier per 32-K step) + XOR chunk swizzle:
// staging lane tid -> row srow=tid>>2, chunk (tid&3)^(srow&3); fragment read
// at chunk quad^(col0&3). 2-way LDS aliasing only (free per m136).
__device__ __forceinline__ void gemm128_mainloop(
    const unsigned short* __restrict__ A,
    const unsigned short* __restrict__ Bt,
    int Kdim, int tileM, int tileN, int tid,
    unsigned short* As0, unsigned short* Bs0,
    unsigned short* As1, unsigned short* Bs1,
    f32x4 (&acc)[4][4]) {

    const int lane = tid & 63;
    const int quad = lane >> 4;
    const int col0 = lane & 15;
    const int wr = tid >> 7;          // wave row (0/1)
    const int wc = (tid >> 6) & 1;    // wave col (0/1)

    const int srow = tid >> 2;                       // 0..63
    const int schunk = ((tid & 3) ^ (srow & 3)) * 8; // swizzled chunk offset
    const unsigned short* Ab = A + (size_t)(tileM + srow) * Kdim + schunk;
    const unsigned short* Bb = Bt + (size_t)(tileN + srow) * Kdim + schunk;
    const size_t rowskip = (size_t)64 * Kdim;        // row+64: same swizzle (64%4==0)

    unsigned short* AsB[2] = {As0, As1};
    unsigned short* BsB[2] = {Bs0, Bs1};

    const int fchunk = (quad ^ (col0 & 3)) * 8;      // fragment read chunk
    const int nkt = Kdim >> 5;

    // prologue: stage k-chunk 0 into buf0
    {
        char* AsD = (char*)As0 + tid * 16;
        char* BsD = (char*)Bs0 + tid * 16;
        async16(Ab, AsD);
        async16(Ab + rowskip, AsD + 4096);
        async16(Bb, BsD);
        async16(Bb + rowskip, BsD + 4096);
    }

    for (int kt = 0; kt < nkt; ++kt) {
        __syncthreads();   // publishes buf[kt&1] (vmcnt drained by compiler)

        if (kt + 1 < nkt) {          // prefetch next chunk into other buffer
            int k0 = (kt + 1) << 5;
            char* AsD = (char*)AsB[(kt + 1) & 1] + tid * 16;
            char* BsD = (char*)BsB[(kt + 1) & 1] + tid * 16;
            async16(Ab + k0, AsD);
            async16(Ab + k0 + rowskip, AsD + 4096);
            async16(Bb + k0, BsD);
            async16(Bb + k0 + rowskip, BsD + 4096);
        }

        const unsigned short* Asc = AsB[kt & 1];
        const unsigned short* Bsc = BsB[kt & 1];

        bf16x8 af[4], bfr[4];
#pragma unroll
        for (int rt = 0; rt < 4; ++rt)
            af[rt] = *reinterpret_cast<const bf16x8*>(
                Asc + (wr * 64 + rt * 16 + col0) * 32 + fchunk);
#pragma unroll
        for (int ct = 0; ct < 4; ++ct)
            bfr[ct] = *reinterpret_cast<const bf16x8*>(
                Bsc + (wc * 64 + ct * 16 + col0) * 32 + fchunk);
#pragma unroll
        for (int rt = 0; rt < 4; ++rt)
#pragma unroll
            for (int ct = 0; ct < 4; ++ct)
                acc[rt][ct] = __builtin_amdgcn_mfma_f32_16x16x32_bf16(
                    af[rt], bfr[ct], acc[rt][ct], 0, 0, 0);
    }
}

// ---------------- QKV projection GEMM ----------------
// Q written PRE-SCALED by QSCALE; V written transposed [B,H,64,S]
__global__ __launch_bounds__(256) void gemm_qkv(
    const unsigned short* __restrict__ xb,
    const unsigned short* __restrict__ wqkv,
    unsigned short* __restrict__ Qd,
    unsigned short* __restrict__ Kd,
    unsigned short* __restrict__ Vtd) {

    __shared__ __align__(16) unsigned short As0[128 * 32];
    __shared__ __align__(16) unsigned short Bs0[128 * 32];
    __shared__ __align__(16) unsigned short As1[128 * 32];
    __shared__ __align__(16) unsigned short Bs1[128 * 32];
    const int tid = threadIdx.x;
    const int tileN = blockIdx.x * 128;
    const int tileM = blockIdx.y * 128;

    f32x4 acc[4][4];
    const f32x4 z = {0.f, 0.f, 0.f, 0.f};
#pragma unroll
    for (int i = 0; i < 4; ++i)
#pragma unroll
        for (int j = 0; j < 4; ++j) acc[i][j] = z;

    gemm128_mainloop(xb, wqkv, SD, tileM, tileN, tid, As0, Bs0, As1, Bs1, acc);

    const int lane = tid & 63, quad = lane >> 4, col0 = lane & 15;
    const int wr = tid >> 7, wc = (tid >> 6) & 1;

#pragma unroll
    for (int ct = 0; ct < 4; ++ct) {
        int n0 = tileN + wc * 64 + ct * 16;   // 16-col tile, uniform which/h
        int which = n0 >> 10;
        int e0 = n0 & 1023;
        int h = e0 >> 6;
        int hd = (e0 & 63) + col0;
#pragma unroll
        for (int rt = 0; rt < 4; ++rt) {
            int m0 = tileM + wr * 64 + rt * 16 + quad * 4;
            int bb = m0 >> 11;
            int s0 = m0 & 2047;
            int bh = bb * SH + h;
            if (which == 0) {
                int base = (bh * SS + s0) * SHD + hd;
#pragma unroll
                for (int r = 0; r < 4; ++r)
                    Qd[base + r * SHD] = f2bf(acc[rt][ct][r] * QSCALE);
            } else if (which == 1) {
                int base = (bh * SS + s0) * SHD + hd;
#pragma unroll
                for (int r = 0; r < 4; ++r)
                    Kd[base + r * SHD] = f2bf(acc[rt][ct][r]);
            } else {
                int base = (bh * SHD + hd) * SS + s0;  // transposed V
                ushort4 pk;
                pk.x = f2bf(acc[rt][ct][0]);
                pk.y = f2bf(acc[rt][ct][1]);
                pk.z = f2bf(acc[rt][ct][2]);
                pk.w = f2bf(acc[rt][ct][3]);
                *reinterpret_cast<ushort4*>(Vtd + base) = pk;
            }
        }
    }
}

// ---------------- output projection GEMM (+bias, fp32 out) ----------------
__global__ __launch_bounds__(256) void gemm_out(
    const unsigned short* __restrict__ ctx,
    const unsigned short* __restrict__ wo16,
    const float* __restrict__ wb,
    float* __restrict__ out) {

    __shared__ __align__(16) unsigned short As0[128 * 32];
    __shared__ __align__(16) unsigned short Bs0[128 * 32];
    __shared__ __align__(16) unsigned short As1[128 * 32];
    __shared__ __align__(16) unsigned short Bs1[128 * 32];
    const int tid = threadIdx.x;
    const int tileN = blockIdx.x * 128;
    const int tileM = blockIdx.y * 128;

    f32x4 acc[4][4];
    const f32x4 z = {0.f, 0.f, 0.f, 0.f};
#pragma unroll
    for (int i = 0; i < 4; ++i)
#pragma unroll
        for (int j = 0; j < 4; ++j) acc[i][j] = z;

    gemm128_mainloop(ctx, wo16, SD, tileM, tileN, tid, As0, Bs0, As1, Bs1, acc);

    const int lane = tid & 63, quad = lane >> 4, col0 = lane & 15;
    const int wr = tid >> 7, wc = (tid >> 6) & 1;

#pragma unroll
    for (int ct = 0; ct < 4; ++ct) {
        int n = tileN + wc * 64 + ct * 16 + col0;
        float bias = wb[n];
#pragma unroll
        for (int rt = 0; rt < 4; ++rt) {
            int m0 = tileM + wr * 64 + rt * 16 + quad * 4;
#pragma unroll
            for (int r = 0; r < 4; ++r)
                out[(size_t)(m0 + r) * SD + n] = acc[rt][ct][r] + bias;
        }
    }
}

// ---------------- flash attention v5 (unchanged from R5) ----------------
#define PSTR 72

__device__ __forceinline__ void attn_pass(
    const unsigned short* __restrict__ Qg,
    const unsigned short* __restrict__ Kg,
    const unsigned short* __restrict__ Vtg,
    unsigned short* __restrict__ ctx,
    size_t base, int b, int h, int jj,
    int tid, int w, int quad, int col0,
    unsigned short* Ks0, unsigned short* Ks1,
    unsigned short* Vs0, unsigned short* Vs1,
    unsigned short* Psw, const bf16x8& ones) {

    const int q0 = jj * 128 + w * 32;     // wave's 32-row base

    // Q fragments (B-operand) for 2 q-groups, held across the k-loop
    bf16x8 bq[2][2];
#pragma unroll
    for (int g = 0; g < 2; ++g)
#pragma unroll
        for (int ks = 0; ks < 2; ++ks)
            bq[g][ks] = *reinterpret_cast<const bf16x8*>(
                Qg + base + (size_t)(q0 + g * 16 + col0) * SHD + ks * 32 + quad * 8);

    f32x4 ot[2][4], lacc[2];
    const f32x4 z = {0.f, 0.f, 0.f, 0.f};
#pragma unroll
    for (int g = 0; g < 2; ++g) {
        lacc[g] = z;
#pragma unroll
        for (int ct = 0; ct < 4; ++ct) ot[g][ct] = z;
    }

    // staging coords (256 threads x 16B x2 issues = 16KB: K 8KB + V 8KB)
    const int srow0 = tid >> 3;                      // 0..31
    const int scs = tid & 7;                         // chunk slot in row

    unsigned short* KsB[2] = {Ks0, Ks1};
    unsigned short* VsB[2] = {Vs0, Vs1};

    const int nkt = 2 * jj + 2;

    // prologue: ensure prior reads of buf0 (previous pass) are done, stage(0)
    __syncthreads();
#pragma unroll
    for (int j = 0; j < 2; ++j) {
        int row = j * 32 + srow0;
        int chunk = scs ^ (row & 7);
        int slot16 = (j * 256 + tid) * 16;
        async16(Kg + base + (size_t)row * SHD + chunk * 8, (char*)Ks0 + slot16);
        async16(Vtg + base + (size_t)row * SS + chunk * 8, (char*)Vs0 + slot16);
    }

    for (int kt = 0; kt < nkt; ++kt) {
        const int kb = kt * 64;
        __syncthreads();   // publishes tile kt (compiler drains vmcnt before barrier)

        // prefetch tile kt+1 into the other buffer
        if (kt + 1 < nkt) {
            const int kb1 = kb + 64;
            unsigned short* Kn = KsB[(kt + 1) & 1];
            unsigned short* Vn = VsB[(kt + 1) & 1];
#pragma unroll
            for (int j = 0; j < 2; ++j) {
                int row = j * 32 + srow0;
                int chunk = scs ^ (row & 7);
                int slot16 = (j * 256 + tid) * 16;
                async16(Kg + base + (size_t)(kb1 + row) * SHD + chunk * 8,
                        (char*)Kn + slot16);
                async16(Vtg + base + (size_t)row * SS + kb1 + chunk * 8,
                        (char*)Vn + slot16);
            }
        }

        if (kb > q0 + 31) continue;   // fully masked for this wave

        const unsigned short* Kc = KsB[kt & 1];
        const unsigned short* Vc = VsB[kt & 1];

        // ---- K fragments from LDS (swizzled), shared by both q-groups ----
        bf16x8 ak[4][2];
#pragma unroll
        for (int rt = 0; rt < 4; ++rt)
#pragma unroll
            for (int ks = 0; ks < 2; ++ks)
                ak[rt][ks] = *reinterpret_cast<const bf16x8*>(
                    &Kc[(rt * 16 + col0) * 64 + ((ks * 4 + quad) ^ (col0 & 7)) * 8]);

        // ---- S^T = K Q^T, both groups ----
        f32x4 sc[2][4];
#pragma unroll
        for (int g = 0; g < 2; ++g)
#pragma unroll
            for (int rt = 0; rt < 4; ++rt) sc[g][rt] = z;
#pragma unroll
        for (int rt = 0; rt < 4; ++rt)
#pragma unroll
            for (int g = 0; g < 2; ++g) {
                sc[g][rt] = __builtin_amdgcn_mfma_f32_16x16x32_bf16(
                    ak[rt][0], bq[g][0], sc[g][rt], 0, 0, 0);
                sc[g][rt] = __builtin_amdgcn_mfma_f32_16x16x32_bf16(
                    ak[rt][1], bq[g][1], sc[g][rt], 0, 0, 0);
            }

        // ---- causal mask (diagonal tiles only; wave-uniform check) ----
        if (kb + 63 > q0) {
#pragma unroll
            for (int g = 0; g < 2; ++g) {
                int q = q0 + g * 16 + col0;
#pragma unroll
                for (int rt = 0; rt < 4; ++rt)
#pragma unroll
                    for (int r = 0; r < 4; ++r) {
                        int key = kb + rt * 16 + quad * 4 + r;
                        if (key > q) sc[g][rt][r] = -3.0e38f;
                    }
            }
        }

        // ---- P = exp2(S) (fixed base m=0; masked -> 0) ----
#pragma unroll
        for (int g = 0; g < 2; ++g)
#pragma unroll
            for (int rt = 0; rt < 4; ++rt)
#pragma unroll
                for (int r = 0; r < 4; ++r)
                    sc[g][rt][r] = fast_exp2(sc[g][rt][r]);

        // ---- P -> per-wave-per-group LDS (packed 8B), C-layout -> B-op ----
#pragma unroll
        for (int g = 0; g < 2; ++g) {
            unsigned short* Pw = Psw + g * 16 * PSTR;
#pragma unroll
            for (int rt = 0; rt < 4; ++rt) {
                uint2 pk;
                pk.x = pkhi(sc[g][rt][1], sc[g][rt][0]);
                pk.y = pkhi(sc[g][rt][3], sc[g][rt][2]);
                *reinterpret_cast<uint2*>(&Pw[col0 * PSTR + rt * 16 + quad * 4]) = pk;
            }
        }

        // ---- O^T += V^T P ; l += 1^T P (row-sum via ones MFMA) ----
#pragma unroll
        for (int ks = 0; ks < 2; ++ks) {
            bf16x8 bp[2];
#pragma unroll
            for (int g = 0; g < 2; ++g) {
                bp[g] = *reinterpret_cast<const bf16x8*>(
                    &Psw[g * 16 * PSTR + col0 * PSTR + ks * 32 + quad * 8]);
                lacc[g] = __builtin_amdgcn_mfma_f32_16x16x32_bf16(
                    ones, bp[g], lacc[g], 0, 0, 0);
            }
#pragma unroll
            for (int ct = 0; ct < 4; ++ct) {
                bf16x8 av = *reinterpret_cast<const bf16x8*>(
                    &Vc[(ct * 16 + col0) * 64 + ((ks * 4 + quad) ^ (col0 & 7)) * 8]);
#pragma unroll
                for (int g = 0; g < 2; ++g)
                    ot[g][ct] = __builtin_amdgcn_mfma_f32_16x16x32_bf16(
                        av, bp[g], ot[g][ct], 0, 0, 0);
            }
        }
    }

    // ---- epilogue: ctx[b][q][h*64+hd]; O^T col=q, row=hd; l = lacc[.][0] ----
#pragma unroll
    for (int g = 0; g < 2; ++g) {
        float inv = 1.0f / lacc[g][0];
        int q = q0 + g * 16 + col0;
        size_t obase = ((size_t)b * SS + q) * SD + h * SHD;
#pragma unroll
        for (int ct = 0; ct < 4; ++ct) {
            uint2 pk;
            pk.x = pkhi(ot[g][ct][1] * inv, ot[g][ct][0] * inv);
            pk.y = pkhi(ot[g][ct][3] * inv, ot[g][ct][2] * inv);
            *reinterpret_cast<uint2*>(ctx + obase + ct * 16 + quad * 4) = pk;
        }
    }
}

__global__ __launch_bounds__(256) void attn_kernel(
    const unsigned short* __restrict__ Qg,
    const unsigned short* __restrict__ Kg,
    const unsigned short* __restrict__ Vtg,
    unsigned short* __restrict__ ctx) {

    __shared__ __align__(16) unsigned short Ks0[64 * 64];      // XOR-swizzled
    __shared__ __align__(16) unsigned short Ks1[64 * 64];
    __shared__ __align__(16) unsigned short Vs0[64 * 64];
    __shared__ __align__(16) unsigned short Vs1[64 * 64];
    __shared__ __align__(16) unsigned short Ps[8 * 16 * PSTR]; // wave x group

    const int tid = threadIdx.x;
    const int w = tid >> 6;
    const int lane = tid & 63;
    const int quad = lane >> 4;
    const int col0 = lane & 15;
    const int bh = blockIdx.y;
    const int b = bh >> 4;
    const int h = bh & 15;
    const size_t base = (size_t)bh * (SS * SHD);
    unsigned short* Psw = Ps + w * 2 * 16 * PSTR;

    bf16x8 ones;
#pragma unroll
    for (int i = 0; i < 8; ++i) ones[i] = (__bf16)1.0f;

    // paired q-tiles jj and 15-jj -> uniform 34 k-tiles per block
    attn_pass(Qg, Kg, Vtg, ctx, base, b, h, blockIdx.x,
              tid, w, quad, col0, Ks0, Ks1, Vs0, Vs1, Psw, ones);
    attn_pass(Qg, Kg, Vtg, ctx, base, b, h, 15 - blockIdx.x,
              tid, w, quad, col0, Ks0, Ks1, Vs0, Vs1, Psw, ones);
}

// ---------------- launcher ----------------
// ws layout (bytes):
//  xb    @ 0          16,777,216
//  wqkv  @ 16777216    6,291,456
//  q     @ 23068672   16,777,216
//  k     @ 39845888   16,777,216
//  vt    @ 56623104   16,777,216
//  ctx   @ 73400320   16,777,216
//  wo16  @ 90177536    2,097,152   total 92,274,688
extern "C" void kernel_launch(void* const* d_in, const int* in_sizes, int n_in,
                              void* d_out, int out_size, void* d_ws, size_t ws_size,
                              hipStream_t stream) {
    const float* x  = (const float*)d_in[0];
    const float* wq = (const float*)d_in[1];
    const float* wk = (const float*)d_in[2];
    const float* wv = (const float*)d_in[3];
    const float* wo = (const float*)d_in[4];
    const float* wb = (const float*)d_in[5];
    float* out = (float*)d_out;

    char* ws = (char*)d_ws;
    unsigned short* xb   = (unsigned short*)(ws + 0);
    unsigned short* wqkv = (unsigned short*)(ws + 16777216);
    unsigned short* q    = (unsigned short*)(ws + 23068672);
    unsigned short* k    = (unsigned short*)(ws + 39845888);
    unsigned short* vt   = (unsigned short*)(ws + 56623104);
    unsigned short* ctx  = (unsigned short*)(ws + 73400320);
    unsigned short* wo16 = (unsigned short*)(ws + 90177536);

    // fused casts: 3145728 float4 units / 256 = 12288 blocks
    cast_all<<<12288, 256, 0, stream>>>(x, wq, wk, wv, wo, xb, wqkv, wo16);

    // QKV projection: M=8192, N=3072
    gemm_qkv<<<dim3(3 * SD / 128, SM / 128), 256, 0, stream>>>(xb, wqkv, q, k, vt);

    // attention: grid (8 pair-tiles, B*H)
    attn_kernel<<<dim3(8, SB * SH), 256, 0, stream>>>(q, k, vt, ctx);

    // output projection: M=8192, N=1024, +bias, fp32 out
    gemm_out<<<dim3(SD / 128, SM / 128), 256, 0, stream>>>(ctx, wo16, wb, out);
}

// Round 7
// 262.035 us; speedup vs baseline: 1.1295x; 1.1295x over previous
//
#include <hip/hip_runtime.h>

// ---------------- problem constants ----------------
// B=4, S=2048, D=1024, H=16, HD=64; M = B*S = 8192
#define SB 4
#define SS 2048
#define SD 1024
#define SH 16
#define SHD 64
#define SM (SB * SS)   // 8192

typedef __bf16 bf16x8 __attribute__((ext_vector_type(8)));
typedef float f32x4 __attribute__((ext_vector_type(4)));

static __device__ __forceinline__ unsigned short f2bf(float x) {
    unsigned int u = __builtin_bit_cast(unsigned int, x);
    u += 0x7fffu + ((u >> 16) & 1u);   // RNE (no NaNs in this problem)
    return (unsigned short)(u >> 16);
}

static __device__ __forceinline__ float fast_exp2(float x) {
#if __has_builtin(__builtin_amdgcn_exp2f)
    return __builtin_amdgcn_exp2f(x);
#else
    return exp2f(x);
#endif
}

// pack high16(a)<<16 | high16(b) via v_perm_b32 (bf16 truncation, 1 inst / 2 vals)
static __device__ __forceinline__ unsigned int pkhi(float a, float b) {
    return __builtin_amdgcn_perm(__builtin_bit_cast(unsigned int, a),
                                 __builtin_bit_cast(unsigned int, b), 0x07060302u);
}

typedef __attribute__((address_space(1))) void GV;
typedef __attribute__((address_space(3))) void LV;

static __device__ __forceinline__ void async16(const void* g, void* l) {
    __builtin_amdgcn_global_load_lds((GV*)g, (LV*)l, 16, 0, 0);
}

// Q pre-scale: 1/sqrt(64) * log2(e) -> softmax runs natively in log2 domain
#define QSCALE 0.18033688011112042f

// ---------------- fused cast fp32 -> bf16 (x, wq, wk, wv, wo in one launch) ----
__global__ __launch_bounds__(256) void cast_all(
    const float* __restrict__ x,  const float* __restrict__ wq,
    const float* __restrict__ wk, const float* __restrict__ wv,
    const float* __restrict__ wo,
    unsigned short* __restrict__ xb, unsigned short* __restrict__ wqkv,
    unsigned short* __restrict__ wo16) {
    int i = blockIdx.x * 256 + threadIdx.x;
    const float4* src;
    ushort4* dst;
    if (i < 2097152) {
        src = reinterpret_cast<const float4*>(x) + i;
        dst = reinterpret_cast<ushort4*>(xb) + i;
    } else {
        int j = i - 2097152;
        int which = j >> 18;          // 262144 float4 per weight
        int r = j & 262143;
        const float* ws_[4] = {wq, wk, wv, wo};
        src = reinterpret_cast<const float4*>(ws_[which]) + r;
        dst = (which < 3 ? reinterpret_cast<ushort4*>(wqkv) + which * 262144
                         : reinterpret_cast<ushort4*>(wo16)) + r;
    }
    float4 v = *src;
    ushort4 o;
    o.x = f2bf(v.x); o.y = f2bf(v.y); o.z = f2bf(v.z); o.w = f2bf(v.w);
    *dst = o;
}

// ---------------- 128x128 GEMM mainloop v3 ----------------
// Single barrier per 32-K step, double-buffered with STATIC schedule:
// K-loop unrolled by 2 (even step reads buf0 / prefetches buf1, odd step
// reads buf1 / prefetches buf0) -> no dynamic pointer selects (R6 lesson:
// dynamic buffer arrays drove VGPR 104->68 and VALUBusy 15->44%).
// Kdim hardcoded = SD (1024), nkt = 32.
__device__ __forceinline__ void gemm128_compute(
    const unsigned short* __restrict__ Asc,
    const unsigned short* __restrict__ Bsc,
    int wr, int wc, int col0, int fchunk, f32x4 (&acc)[4][4]) {
    bf16x8 af[4], bfr[4];
#pragma unroll
    for (int rt = 0; rt < 4; ++rt)
        af[rt] = *reinterpret_cast<const bf16x8*>(
            Asc + (wr * 64 + rt * 16 + col0) * 32 + fchunk);
#pragma unroll
    for (int ct = 0; ct < 4; ++ct)
        bfr[ct] = *reinterpret_cast<const bf16x8*>(
            Bsc + (wc * 64 + ct * 16 + col0) * 32 + fchunk);
#pragma unroll
    for (int rt = 0; rt < 4; ++rt)
#pragma unroll
        for (int ct = 0; ct < 4; ++ct)
            acc[rt][ct] = __builtin_amdgcn_mfma_f32_16x16x32_bf16(
                af[rt], bfr[ct], acc[rt][ct], 0, 0, 0);
}

__device__ __forceinline__ void gemm128_mainloop(
    const unsigned short* __restrict__ A,
    const unsigned short* __restrict__ Bt,
    int tileM, int tileN, int tid,
    unsigned short* As0, unsigned short* Bs0,
    unsigned short* As1, unsigned short* Bs1,
    f32x4 (&acc)[4][4]) {

    const int lane = tid & 63;
    const int quad = lane >> 4;
    const int col0 = lane & 15;
    const int wr = tid >> 7;          // wave row (0/1)
    const int wc = (tid >> 6) & 1;    // wave col (0/1)

    const int srow = tid >> 2;                       // 0..63
    const int schunk = ((tid & 3) ^ (srow & 3)) * 8; // swizzled chunk offset
    const unsigned short* Ab = A + (size_t)(tileM + srow) * SD + schunk;
    const unsigned short* Bb = Bt + (size_t)(tileN + srow) * SD + schunk;
    const size_t rowskip = (size_t)64 * SD;          // row+64: same swizzle

    char* As0D = (char*)As0 + tid * 16;
    char* Bs0D = (char*)Bs0 + tid * 16;
    char* As1D = (char*)As1 + tid * 16;
    char* Bs1D = (char*)Bs1 + tid * 16;

    const int fchunk = (quad ^ (col0 & 3)) * 8;      // fragment read chunk

    // prologue: stage k-chunk 0 into buf0
    async16(Ab, As0D);
    async16(Ab + rowskip, As0D + 4096);
    async16(Bb, Bs0D);
    async16(Bb + rowskip, Bs0D + 4096);

#pragma unroll 1
    for (int kt = 0; kt < 32; kt += 2) {
        const int ke = (kt + 1) << 5;   // global elem offset of odd chunk
        __syncthreads();                 // publish buf0 (chunk kt)
        // prefetch chunk kt+1 -> buf1 (kt+1 <= 31 always)
        async16(Ab + ke, As1D);
        async16(Ab + ke + rowskip, As1D + 4096);
        async16(Bb + ke, Bs1D);
        async16(Bb + ke + rowskip, Bs1D + 4096);
        gemm128_compute(As0, Bs0, wr, wc, col0, fchunk, acc);

        __syncthreads();                 // publish buf1 (chunk kt+1)
        if (kt < 30) {                   // prefetch chunk kt+2 -> buf0
            const int ko = (kt + 2) << 5;
            async16(Ab + ko, As0D);
            async16(Ab + ko + rowskip, As0D + 4096);
            async16(Bb + ko, Bs0D);
            async16(Bb + ko + rowskip, Bs0D + 4096);
        }
        gemm128_compute(As1, Bs1, wr, wc, col0, fchunk, acc);
    }
}

// ---------------- QKV projection GEMM ----------------
// Q written PRE-SCALED by QSCALE; V written transposed [B,H,64,S]
__global__ __launch_bounds__(256) void gemm_qkv(
    const unsigned short* __restrict__ xb,
    const unsigned short* __restrict__ wqkv,
    unsigned short* __restrict__ Qd,
    unsigned short* __restrict__ Kd,
    unsigned short* __restrict__ Vtd) {

    __shared__ __align__(16) unsigned short As0[128 * 32];
    __shared__ __align__(16) unsigned short Bs0[128 * 32];
    __shared__ __align__(16) unsigned short As1[128 * 32];
    __shared__ __align__(16) unsigned short Bs1[128 * 32];
    const int tid = threadIdx.x;
    const int tileN = blockIdx.x * 128;
    const int tileM = blockIdx.y * 128;

    f32x4 acc[4][4];
    const f32x4 z = {0.f, 0.f, 0.f, 0.f};
#pragma unroll
    for (int i = 0; i < 4; ++i)
#pragma unroll
        for (int j = 0; j < 4; ++j) acc[i][j] = z;

    gemm128_mainloop(xb, wqkv, tileM, tileN, tid, As0, Bs0, As1, Bs1, acc);

    const int lane = tid & 63, quad = lane >> 4, col0 = lane & 15;
    const int wr = tid >> 7, wc = (tid >> 6) & 1;

#pragma unroll
    for (int ct = 0; ct < 4; ++ct) {
        int n0 = tileN + wc * 64 + ct * 16;   // 16-col tile, uniform which/h
        int which = n0 >> 10;
        int e0 = n0 & 1023;
        int h = e0 >> 6;
        int hd = (e0 & 63) + col0;
#pragma unroll
        for (int rt = 0; rt < 4; ++rt) {
            int m0 = tileM + wr * 64 + rt * 16 + quad * 4;
            int bb = m0 >> 11;
            int s0 = m0 & 2047;
            int bh = bb * SH + h;
            if (which == 0) {
                int base = (bh * SS + s0) * SHD + hd;
#pragma unroll
                for (int r = 0; r < 4; ++r)
                    Qd[base + r * SHD] = f2bf(acc[rt][ct][r] * QSCALE);
            } else if (which == 1) {
                int base = (bh * SS + s0) * SHD + hd;
#pragma unroll
                for (int r = 0; r < 4; ++r)
                    Kd[base + r * SHD] = f2bf(acc[rt][ct][r]);
            } else {
                int base = (bh * SHD + hd) * SS + s0;  // transposed V
                ushort4 pk;
                pk.x = f2bf(acc[rt][ct][0]);
                pk.y = f2bf(acc[rt][ct][1]);
                pk.z = f2bf(acc[rt][ct][2]);
                pk.w = f2bf(acc[rt][ct][3]);
                *reinterpret_cast<ushort4*>(Vtd + base) = pk;
            }
        }
    }
}

// ---------------- output projection GEMM (+bias, fp32 out) ----------------
__global__ __launch_bounds__(256) void gemm_out(
    const unsigned short* __restrict__ ctx,
    const unsigned short* __restrict__ wo16,
    const float* __restrict__ wb,
    float* __restrict__ out) {

    __shared__ __align__(16) unsigned short As0[128 * 32];
    __shared__ __align__(16) unsigned short Bs0[128 * 32];
    __shared__ __align__(16) unsigned short As1[128 * 32];
    __shared__ __align__(16) unsigned short Bs1[128 * 32];
    const int tid = threadIdx.x;
    const int tileN = blockIdx.x * 128;
    const int tileM = blockIdx.y * 128;

    f32x4 acc[4][4];
    const f32x4 z = {0.f, 0.f, 0.f, 0.f};
#pragma unroll
    for (int i = 0; i < 4; ++i)
#pragma unroll
        for (int j = 0; j < 4; ++j) acc[i][j] = z;

    gemm128_mainloop(ctx, wo16, tileM, tileN, tid, As0, Bs0, As1, Bs1, acc);

    const int lane = tid & 63, quad = lane >> 4, col0 = lane & 15;
    const int wr = tid >> 7, wc = (tid >> 6) & 1;

#pragma unroll
    for (int ct = 0; ct < 4; ++ct) {
        int n = tileN + wc * 64 + ct * 16 + col0;
        float bias = wb[n];
#pragma unroll
        for (int rt = 0; rt < 4; ++rt) {
            int m0 = tileM + wr * 64 + rt * 16 + quad * 4;
#pragma unroll
            for (int r = 0; r < 4; ++r)
                out[(size_t)(m0 + r) * SD + n] = acc[rt][ct][r] + bias;
        }
    }
}

// ---------------- flash attention v5 (unchanged from R5) ----------------
#define PSTR 72

__device__ __forceinline__ void attn_pass(
    const unsigned short* __restrict__ Qg,
    const unsigned short* __restrict__ Kg,
    const unsigned short* __restrict__ Vtg,
    unsigned short* __restrict__ ctx,
    size_t base, int b, int h, int jj,
    int tid, int w, int quad, int col0,
    unsigned short* Ks0, unsigned short* Ks1,
    unsigned short* Vs0, unsigned short* Vs1,
    unsigned short* Psw, const bf16x8& ones) {

    const int q0 = jj * 128 + w * 32;     // wave's 32-row base

    // Q fragments (B-operand) for 2 q-groups, held across the k-loop
    bf16x8 bq[2][2];
#pragma unroll
    for (int g = 0; g < 2; ++g)
#pragma unroll
        for (int ks = 0; ks < 2; ++ks)
            bq[g][ks] = *reinterpret_cast<const bf16x8*>(
                Qg + base + (size_t)(q0 + g * 16 + col0) * SHD + ks * 32 + quad * 8);

    f32x4 ot[2][4], lacc[2];
    const f32x4 z = {0.f, 0.f, 0.f, 0.f};
#pragma unroll
    for (int g = 0; g < 2; ++g) {
        lacc[g] = z;
#pragma unroll
        for (int ct = 0; ct < 4; ++ct) ot[g][ct] = z;
    }

    // staging coords (256 threads x 16B x2 issues = 16KB: K 8KB + V 8KB)
    const int srow0 = tid >> 3;                      // 0..31
    const int scs = tid & 7;                         // chunk slot in row

    unsigned short* KsB[2] = {Ks0, Ks1};
    unsigned short* VsB[2] = {Vs0, Vs1};

    const int nkt = 2 * jj + 2;

    // prologue: ensure prior reads of buf0 (previous pass) are done, stage(0)
    __syncthreads();
#pragma unroll
    for (int j = 0; j < 2; ++j) {
        int row = j * 32 + srow0;
        int chunk = scs ^ (row & 7);
        int slot16 = (j * 256 + tid) * 16;
        async16(Kg + base + (size_t)row * SHD + chunk * 8, (char*)Ks0 + slot16);
        async16(Vtg + base + (size_t)row * SS + chunk * 8, (char*)Vs0 + slot16);
    }

    for (int kt = 0; kt < nkt; ++kt) {
        const int kb = kt * 64;
        __syncthreads();   // publishes tile kt (compiler drains vmcnt before barrier)

        // prefetch tile kt+1 into the other buffer
        if (kt + 1 < nkt) {
            const int kb1 = kb + 64;
            unsigned short* Kn = KsB[(kt + 1) & 1];
            unsigned short* Vn = VsB[(kt + 1) & 1];
#pragma unroll
            for (int j = 0; j < 2; ++j) {
                int row = j * 32 + srow0;
                int chunk = scs ^ (row & 7);
                int slot16 = (j * 256 + tid) * 16;
                async16(Kg + base + (size_t)(kb1 + row) * SHD + chunk * 8,
                        (char*)Kn + slot16);
                async16(Vtg + base + (size_t)row * SS + kb1 + chunk * 8,
                        (char*)Vn + slot16);
            }
        }

        if (kb > q0 + 31) continue;   // fully masked for this wave

        const unsigned short* Kc = KsB[kt & 1];
        const unsigned short* Vc = VsB[kt & 1];

        // ---- K fragments from LDS (swizzled), shared by both q-groups ----
        bf16x8 ak[4][2];
#pragma unroll
        for (int rt = 0; rt < 4; ++rt)
#pragma unroll
            for (int ks = 0; ks < 2; ++ks)
                ak[rt][ks] = *reinterpret_cast<const bf16x8*>(
                    &Kc[(rt * 16 + col0) * 64 + ((ks * 4 + quad) ^ (col0 & 7)) * 8]);

        // ---- S^T = K Q^T, both groups ----
        f32x4 sc[2][4];
#pragma unroll
        for (int g = 0; g < 2; ++g)
#pragma unroll
            for (int rt = 0; rt < 4; ++rt) sc[g][rt] = z;
#pragma unroll
        for (int rt = 0; rt < 4; ++rt)
#pragma unroll
            for (int g = 0; g < 2; ++g) {
                sc[g][rt] = __builtin_amdgcn_mfma_f32_16x16x32_bf16(
                    ak[rt][0], bq[g][0], sc[g][rt], 0, 0, 0);
                sc[g][rt] = __builtin_amdgcn_mfma_f32_16x16x32_bf16(
                    ak[rt][1], bq[g][1], sc[g][rt], 0, 0, 0);
            }

        // ---- causal mask (diagonal tiles only; wave-uniform check) ----
        if (kb + 63 > q0) {
#pragma unroll
            for (int g = 0; g < 2; ++g) {
                int q = q0 + g * 16 + col0;
#pragma unroll
                for (int rt = 0; rt < 4; ++rt)
#pragma unroll
                    for (int r = 0; r < 4; ++r) {
                        int key = kb + rt * 16 + quad * 4 + r;
                        if (key > q) sc[g][rt][r] = -3.0e38f;
                    }
            }
        }

        // ---- P = exp2(S) (fixed base m=0; masked -> 0) ----
#pragma unroll
        for (int g = 0; g < 2; ++g)
#pragma unroll
            for (int rt = 0; rt < 4; ++rt)
#pragma unroll
                for (int r = 0; r < 4; ++r)
                    sc[g][rt][r] = fast_exp2(sc[g][rt][r]);

        // ---- P -> per-wave-per-group LDS (packed 8B), C-layout -> B-op ----
#pragma unroll
        for (int g = 0; g < 2; ++g) {
            unsigned short* Pw = Psw + g * 16 * PSTR;
#pragma unroll
            for (int rt = 0; rt < 4; ++rt) {
                uint2 pk;
                pk.x = pkhi(sc[g][rt][1], sc[g][rt][0]);
                pk.y = pkhi(sc[g][rt][3], sc[g][rt][2]);
                *reinterpret_cast<uint2*>(&Pw[col0 * PSTR + rt * 16 + quad * 4]) = pk;
            }
        }

        // ---- O^T += V^T P ; l += 1^T P (row-sum via ones MFMA) ----
#pragma unroll
        for (int ks = 0; ks < 2; ++ks) {
            bf16x8 bp[2];
#pragma unroll
            for (int g = 0; g < 2; ++g) {
                bp[g] = *reinterpret_cast<const bf16x8*>(
                    &Psw[g * 16 * PSTR + col0 * PSTR + ks * 32 + quad * 8]);
                lacc[g] = __builtin_amdgcn_mfma_f32_16x16x32_bf16(
                    ones, bp[g], lacc[g], 0, 0, 0);
            }
#pragma unroll
            for (int ct = 0; ct < 4; ++ct) {
                bf16x8 av = *reinterpret_cast<const bf16x8*>(
                    &Vc[(ct * 16 + col0) * 64 + ((ks * 4 + quad) ^ (col0 & 7)) * 8]);
#pragma unroll
                for (int g = 0; g < 2; ++g)
                    ot[g][ct] = __builtin_amdgcn_mfma_f32_16x16x32_bf16(
                        av, bp[g], ot[g][ct], 0, 0, 0);
            }
        }
    }

    // ---- epilogue: ctx[b][q][h*64+hd]; O^T col=q, row=hd; l = lacc[.][0] ----
#pragma unroll
    for (int g = 0; g < 2; ++g) {
        float inv = 1.0f / lacc[g][0];
        int q = q0 + g * 16 + col0;
        size_t obase = ((size_t)b * SS + q) * SD + h * SHD;
#pragma unroll
        for (int ct = 0; ct < 4; ++ct) {
            uint2 pk;
            pk.x = pkhi(ot[g][ct][1] * inv, ot[g][ct][0] * inv);
            pk.y = pkhi(ot[g][ct][3] * inv, ot[g][ct][2] * inv);
            *reinterpret_cast<uint2*>(ctx + obase + ct * 16 + quad * 4) = pk;
        }
    }
}

__global__ __launch_bounds__(256) void attn_kernel(
    const unsigned short* __restrict__ Qg,
    const unsigned short* __restrict__ Kg,
    const unsigned short* __restrict__ Vtg,
    unsigned short* __restrict__ ctx) {

    __shared__ __align__(16) unsigned short Ks0[64 * 64];      // XOR-swizzled
    __shared__ __align__(16) unsigned short Ks1[64 * 64];
    __shared__ __align__(16) unsigned short Vs0[64 * 64];
    __shared__ __align__(16) unsigned short Vs1[64 * 64];
    __shared__ __align__(16) unsigned short Ps[8 * 16 * PSTR]; // wave x group

    const int tid = threadIdx.x;
    const int w = tid >> 6;
    const int lane = tid & 63;
    const int quad = lane >> 4;
    const int col0 = lane & 15;
    const int bh = blockIdx.y;
    const int b = bh >> 4;
    const int h = bh & 15;
    const size_t base = (size_t)bh * (SS * SHD);
    unsigned short* Psw = Ps + w * 2 * 16 * PSTR;

    bf16x8 ones;
#pragma unroll
    for (int i = 0; i < 8; ++i) ones[i] = (__bf16)1.0f;

    // paired q-tiles jj and 15-jj -> uniform 34 k-tiles per block
    attn_pass(Qg, Kg, Vtg, ctx, base, b, h, blockIdx.x,
              tid, w, quad, col0, Ks0, Ks1, Vs0, Vs1, Psw, ones);
    attn_pass(Qg, Kg, Vtg, ctx, base, b, h, 15 - blockIdx.x,
              tid, w, quad, col0, Ks0, Ks1, Vs0, Vs1, Psw, ones);
}

// ---------------- launcher ----------------
// ws layout (bytes):
//  xb    @ 0          16,777,216
//  wqkv  @ 16777216    6,291,456
//  q     @ 23068672   16,777,216
//  k     @ 39845888   16,777,216
//  vt    @ 56623104   16,777,216
//  ctx   @ 73400320   16,777,216
//  wo16  @ 90177536    2,097,152   total 92,274,688
extern "C" void kernel_launch(void* const* d_in, const int* in_sizes, int n_in,
                              void* d_out, int out_size, void* d_ws, size_t ws_size,
                              hipStream_t stream) {
    const float* x  = (const float*)d_in[0];
    const float* wq = (const float*)d_in[1];
    const float* wk = (const float*)d_in[2];
    const float* wv = (const float*)d_in[3];
    const float* wo = (const float*)d_in[4];
    const float* wb = (const float*)d_in[5];
    float* out = (float*)d_out;

    char* ws = (char*)d_ws;
    unsigned short* xb   = (unsigned short*)(ws + 0);
    unsigned short* wqkv = (unsigned short*)(ws + 16777216);
    unsigned short* q    = (unsigned short*)(ws + 23068672);
    unsigned short* k    = (unsigned short*)(ws + 39845888);
    unsigned short* vt   = (unsigned short*)(ws + 56623104);
    unsigned short* ctx  = (unsigned short*)(ws + 73400320);
    unsigned short* wo16 = (unsigned short*)(ws + 90177536);

    // fused casts: 3145728 float4 units / 256 = 12288 blocks
    cast_all<<<12288, 256, 0, stream>>>(x, wq, wk, wv, wo, xb, wqkv, wo16);

    // QKV projection: M=8192, N=3072
    gemm_qkv<<<dim3(3 * SD / 128, SM / 128), 256, 0, stream>>>(xb, wqkv, q, k, vt);

    // attention: grid (8 pair-tiles, B*H)
    attn_kernel<<<dim3(8, SB * SH), 256, 0, stream>>>(q, k, vt, ctx);

    // output projection: M=8192, N=1024, +bias, fp32 out
    gemm_out<<<dim3(SD / 128, SM / 128), 256, 0, stream>>>(ctx, wo16, wb, out);
}

// Round 8
// 249.967 us; speedup vs baseline: 1.1840x; 1.0483x over previous
//
#include <hip/hip_runtime.h>

// ---------------- problem constants ----------------
// B=4, S=2048, D=1024, H=16, HD=64; M = B*S = 8192
#define SB 4
#define SS 2048
#define SD 1024
#define SH 16
#define SHD 64
#define SM (SB * SS)   // 8192

typedef __bf16 bf16x8 __attribute__((ext_vector_type(8)));
typedef float f32x4 __attribute__((ext_vector_type(4)));

static __device__ __forceinline__ unsigned short f2bf(float x) {
    unsigned int u = __builtin_bit_cast(unsigned int, x);
    u += 0x7fffu + ((u >> 16) & 1u);   // RNE (no NaNs in this problem)
    return (unsigned short)(u >> 16);
}

static __device__ __forceinline__ float fast_exp2(float x) {
#if __has_builtin(__builtin_amdgcn_exp2f)
    return __builtin_amdgcn_exp2f(x);
#else
    return exp2f(x);
#endif
}

// pack high16(a)<<16 | high16(b) via v_perm_b32 (bf16 truncation, 1 inst / 2 vals)
static __device__ __forceinline__ unsigned int pkhi(float a, float b) {
    return __builtin_amdgcn_perm(__builtin_bit_cast(unsigned int, a),
                                 __builtin_bit_cast(unsigned int, b), 0x07060302u);
}

typedef __attribute__((address_space(1))) void GV;
typedef __attribute__((address_space(3))) void LV;

static __device__ __forceinline__ void async16(const void* g, void* l) {
    __builtin_amdgcn_global_load_lds((GV*)g, (LV*)l, 16, 0, 0);
}

// Q pre-scale: 1/sqrt(64) * log2(e) -> softmax runs natively in log2 domain
#define QSCALE 0.18033688011112042f

// ---------------- fused cast fp32 -> bf16 (x, wq, wk, wv, wo in one launch) ----
__global__ __launch_bounds__(256) void cast_all(
    const float* __restrict__ x,  const float* __restrict__ wq,
    const float* __restrict__ wk, const float* __restrict__ wv,
    const float* __restrict__ wo,
    unsigned short* __restrict__ xb, unsigned short* __restrict__ wqkv,
    unsigned short* __restrict__ wo16) {
    int i = blockIdx.x * 256 + threadIdx.x;
    const float4* src;
    ushort4* dst;
    if (i < 2097152) {
        src = reinterpret_cast<const float4*>(x) + i;
        dst = reinterpret_cast<ushort4*>(xb) + i;
    } else {
        int j = i - 2097152;
        int which = j >> 18;          // 262144 float4 per weight
        int r = j & 262143;
        const float* ws_[4] = {wq, wk, wv, wo};
        src = reinterpret_cast<const float4*>(ws_[which]) + r;
        dst = (which < 3 ? reinterpret_cast<ushort4*>(wqkv) + which * 262144
                         : reinterpret_cast<ushort4*>(wo16)) + r;
    }
    float4 v = *src;
    ushort4 o;
    o.x = f2bf(v.x); o.y = f2bf(v.y); o.z = f2bf(v.z); o.w = f2bf(v.w);
    *dst = o;
}

// ---------------- 128x128 GEMM mainloop v3 (unchanged from R7) ----------------
__device__ __forceinline__ void gemm128_compute(
    const unsigned short* __restrict__ Asc,
    const unsigned short* __restrict__ Bsc,
    int wr, int wc, int col0, int fchunk, f32x4 (&acc)[4][4]) {
    bf16x8 af[4], bfr[4];
#pragma unroll
    for (int rt = 0; rt < 4; ++rt)
        af[rt] = *reinterpret_cast<const bf16x8*>(
            Asc + (wr * 64 + rt * 16 + col0) * 32 + fchunk);
#pragma unroll
    for (int ct = 0; ct < 4; ++ct)
        bfr[ct] = *reinterpret_cast<const bf16x8*>(
            Bsc + (wc * 64 + ct * 16 + col0) * 32 + fchunk);
#pragma unroll
    for (int rt = 0; rt < 4; ++rt)
#pragma unroll
        for (int ct = 0; ct < 4; ++ct)
            acc[rt][ct] = __builtin_amdgcn_mfma_f32_16x16x32_bf16(
                af[rt], bfr[ct], acc[rt][ct], 0, 0, 0);
}

__device__ __forceinline__ void gemm128_mainloop(
    const unsigned short* __restrict__ A,
    const unsigned short* __restrict__ Bt,
    int tileM, int tileN, int tid,
    unsigned short* As0, unsigned short* Bs0,
    unsigned short* As1, unsigned short* Bs1,
    f32x4 (&acc)[4][4]) {

    const int lane = tid & 63;
    const int quad = lane >> 4;
    const int col0 = lane & 15;
    const int wr = tid >> 7;          // wave row (0/1)
    const int wc = (tid >> 6) & 1;    // wave col (0/1)

    const int srow = tid >> 2;                       // 0..63
    const int schunk = ((tid & 3) ^ (srow & 3)) * 8; // swizzled chunk offset
    const unsigned short* Ab = A + (size_t)(tileM + srow) * SD + schunk;
    const unsigned short* Bb = Bt + (size_t)(tileN + srow) * SD + schunk;
    const size_t rowskip = (size_t)64 * SD;          // row+64: same swizzle

    char* As0D = (char*)As0 + tid * 16;
    char* Bs0D = (char*)Bs0 + tid * 16;
    char* As1D = (char*)As1 + tid * 16;
    char* Bs1D = (char*)Bs1 + tid * 16;

    const int fchunk = (quad ^ (col0 & 3)) * 8;      // fragment read chunk

    // prologue: stage k-chunk 0 into buf0
    async16(Ab, As0D);
    async16(Ab + rowskip, As0D + 4096);
    async16(Bb, Bs0D);
    async16(Bb + rowskip, Bs0D + 4096);

#pragma unroll 1
    for (int kt = 0; kt < 32; kt += 2) {
        const int ke = (kt + 1) << 5;   // global elem offset of odd chunk
        __syncthreads();                 // publish buf0 (chunk kt)
        async16(Ab + ke, As1D);
        async16(Ab + ke + rowskip, As1D + 4096);
        async16(Bb + ke, Bs1D);
        async16(Bb + ke + rowskip, Bs1D + 4096);
        gemm128_compute(As0, Bs0, wr, wc, col0, fchunk, acc);

        __syncthreads();                 // publish buf1 (chunk kt+1)
        if (kt < 30) {                   // prefetch chunk kt+2 -> buf0
            const int ko = (kt + 2) << 5;
            async16(Ab + ko, As0D);
            async16(Ab + ko + rowskip, As0D + 4096);
            async16(Bb + ko, Bs0D);
            async16(Bb + ko + rowskip, Bs0D + 4096);
        }
        gemm128_compute(As1, Bs1, wr, wc, col0, fchunk, acc);
    }
}

// ---------------- QKV projection GEMM ----------------
// Q written PRE-SCALED by QSCALE; V written transposed [B,H,64,S]
__global__ __launch_bounds__(256) void gemm_qkv(
    const unsigned short* __restrict__ xb,
    const unsigned short* __restrict__ wqkv,
    unsigned short* __restrict__ Qd,
    unsigned short* __restrict__ Kd,
    unsigned short* __restrict__ Vtd) {

    __shared__ __align__(16) unsigned short As0[128 * 32];
    __shared__ __align__(16) unsigned short Bs0[128 * 32];
    __shared__ __align__(16) unsigned short As1[128 * 32];
    __shared__ __align__(16) unsigned short Bs1[128 * 32];
    const int tid = threadIdx.x;
    const int tileN = blockIdx.x * 128;
    const int tileM = blockIdx.y * 128;

    f32x4 acc[4][4];
    const f32x4 z = {0.f, 0.f, 0.f, 0.f};
#pragma unroll
    for (int i = 0; i < 4; ++i)
#pragma unroll
        for (int j = 0; j < 4; ++j) acc[i][j] = z;

    gemm128_mainloop(xb, wqkv, tileM, tileN, tid, As0, Bs0, As1, Bs1, acc);

    const int lane = tid & 63, quad = lane >> 4, col0 = lane & 15;
    const int wr = tid >> 7, wc = (tid >> 6) & 1;

#pragma unroll
    for (int ct = 0; ct < 4; ++ct) {
        int n0 = tileN + wc * 64 + ct * 16;   // 16-col tile, uniform which/h
        int which = n0 >> 10;
        int e0 = n0 & 1023;
        int h = e0 >> 6;
        int hd = (e0 & 63) + col0;
#pragma unroll
        for (int rt = 0; rt < 4; ++rt) {
            int m0 = tileM + wr * 64 + rt * 16 + quad * 4;
            int bb = m0 >> 11;
            int s0 = m0 & 2047;
            int bh = bb * SH + h;
            if (which == 0) {
                int base = (bh * SS + s0) * SHD + hd;
#pragma unroll
                for (int r = 0; r < 4; ++r)
                    Qd[base + r * SHD] = f2bf(acc[rt][ct][r] * QSCALE);
            } else if (which == 1) {
                int base = (bh * SS + s0) * SHD + hd;
#pragma unroll
                for (int r = 0; r < 4; ++r)
                    Kd[base + r * SHD] = f2bf(acc[rt][ct][r]);
            } else {
                int base = (bh * SHD + hd) * SS + s0;  // transposed V
                ushort4 pk;
                pk.x = f2bf(acc[rt][ct][0]);
                pk.y = f2bf(acc[rt][ct][1]);
                pk.z = f2bf(acc[rt][ct][2]);
                pk.w = f2bf(acc[rt][ct][3]);
                *reinterpret_cast<ushort4*>(Vtd + base) = pk;
            }
        }
    }
}

// ---------------- output projection GEMM (+bias, fp32 out) ----------------
__global__ __launch_bounds__(256) void gemm_out(
    const unsigned short* __restrict__ ctx,
    const unsigned short* __restrict__ wo16,
    const float* __restrict__ wb,
    float* __restrict__ out) {

    __shared__ __align__(16) unsigned short As0[128 * 32];
    __shared__ __align__(16) unsigned short Bs0[128 * 32];
    __shared__ __align__(16) unsigned short As1[128 * 32];
    __shared__ __align__(16) unsigned short Bs1[128 * 32];
    const int tid = threadIdx.x;
    const int tileN = blockIdx.x * 128;
    const int tileM = blockIdx.y * 128;

    f32x4 acc[4][4];
    const f32x4 z = {0.f, 0.f, 0.f, 0.f};
#pragma unroll
    for (int i = 0; i < 4; ++i)
#pragma unroll
        for (int j = 0; j < 4; ++j) acc[i][j] = z;

    gemm128_mainloop(ctx, wo16, tileM, tileN, tid, As0, Bs0, As1, Bs1, acc);

    const int lane = tid & 63, quad = lane >> 4, col0 = lane & 15;
    const int wr = tid >> 7, wc = (tid >> 6) & 1;

#pragma unroll
    for (int ct = 0; ct < 4; ++ct) {
        int n = tileN + wc * 64 + ct * 16 + col0;
        float bias = wb[n];
#pragma unroll
        for (int rt = 0; rt < 4; ++rt) {
            int m0 = tileM + wr * 64 + rt * 16 + quad * 4;
#pragma unroll
            for (int r = 0; r < 4; ++r)
                out[(size_t)(m0 + r) * SD + n] = acc[rt][ct][r] + bias;
        }
    }
}

// ---------------- flash attention v6 ----------------
// 2 k-tiles per barrier interval, 4 static K/V buffer pairs: the vmcnt(0)
// drain at each barrier now waits on loads that have had a FULL 2-tile
// (~1200+ cyc) compute window in flight -> HBM miss latency (~900 cyc)
// covered (depth-1 was the R5/R7 81us limiter). Ps shrunk to per-wave
// single-group (g0 then g1 sequentially, same-wave lgkmcnt ordering; both
// bp register sets held so V-fragment reads stay shared across groups).
// LDS: 8x8KB K/V + 9KB Ps = 73KB -> 2 blocks/CU at grid 512.
#define PSTR 72

__device__ __forceinline__ void stage_kv(
    const unsigned short* __restrict__ Kg,
    const unsigned short* __restrict__ Vtg,
    size_t base, int t, int srow0, int scs, int tid,
    unsigned short* Kb, unsigned short* Vb) {
#pragma unroll
    for (int j = 0; j < 2; ++j) {
        int row = j * 32 + srow0;
        int chunk = scs ^ (row & 7);
        int slot16 = (j * 256 + tid) * 16;
        async16(Kg + base + (size_t)(t * 64 + row) * SHD + chunk * 8,
                (char*)Kb + slot16);
        async16(Vtg + base + (size_t)row * SS + t * 64 + chunk * 8,
                (char*)Vb + slot16);
    }
}

__device__ __forceinline__ void attn_tile(
    const unsigned short* __restrict__ Kc,
    const unsigned short* __restrict__ Vc,
    int kb, int q0, int quad, int col0,
    const bf16x8 (&bq)[2][2], const bf16x8& ones,
    unsigned short* Psw, f32x4 (&ot)[2][4], f32x4 (&lacc)[2]) {

    const f32x4 z = {0.f, 0.f, 0.f, 0.f};

    // ---- K fragments from LDS (swizzled), shared by both q-groups ----
    bf16x8 ak[4][2];
#pragma unroll
    for (int rt = 0; rt < 4; ++rt)
#pragma unroll
        for (int ks = 0; ks < 2; ++ks)
            ak[rt][ks] = *reinterpret_cast<const bf16x8*>(
                &Kc[(rt * 16 + col0) * 64 + ((ks * 4 + quad) ^ (col0 & 7)) * 8]);

    // ---- S^T = K Q^T, both groups ----
    f32x4 sc[2][4];
#pragma unroll
    for (int g = 0; g < 2; ++g)
#pragma unroll
        for (int rt = 0; rt < 4; ++rt) sc[g][rt] = z;
#pragma unroll
    for (int rt = 0; rt < 4; ++rt)
#pragma unroll
        for (int g = 0; g < 2; ++g) {
            sc[g][rt] = __builtin_amdgcn_mfma_f32_16x16x32_bf16(
                ak[rt][0], bq[g][0], sc[g][rt], 0, 0, 0);
            sc[g][rt] = __builtin_amdgcn_mfma_f32_16x16x32_bf16(
                ak[rt][1], bq[g][1], sc[g][rt], 0, 0, 0);
        }

    // ---- causal mask (diagonal tiles only; wave-uniform check) ----
    if (kb + 63 > q0) {
#pragma unroll
        for (int g = 0; g < 2; ++g) {
            int q = q0 + g * 16 + col0;
#pragma unroll
            for (int rt = 0; rt < 4; ++rt)
#pragma unroll
                for (int r = 0; r < 4; ++r) {
                    int key = kb + rt * 16 + quad * 4 + r;
                    if (key > q) sc[g][rt][r] = -3.0e38f;
                }
        }
    }

    // ---- P = exp2(S) (fixed base m=0; masked -> 0) ----
#pragma unroll
    for (int g = 0; g < 2; ++g)
#pragma unroll
        for (int rt = 0; rt < 4; ++rt)
#pragma unroll
            for (int r = 0; r < 4; ++r)
                sc[g][rt][r] = fast_exp2(sc[g][rt][r]);

    // ---- P transform through per-wave LDS: g0 then g1 (same-wave order) ----
    bf16x8 bp[2][2];
#pragma unroll
    for (int g = 0; g < 2; ++g) {
#pragma unroll
        for (int rt = 0; rt < 4; ++rt) {
            uint2 pk;
            pk.x = pkhi(sc[g][rt][1], sc[g][rt][0]);
            pk.y = pkhi(sc[g][rt][3], sc[g][rt][2]);
            *reinterpret_cast<uint2*>(&Psw[col0 * PSTR + rt * 16 + quad * 4]) = pk;
        }
#pragma unroll
        for (int ks = 0; ks < 2; ++ks)
            bp[g][ks] = *reinterpret_cast<const bf16x8*>(
                &Psw[col0 * PSTR + ks * 32 + quad * 8]);
    }

    // ---- O^T += V^T P ; l += 1^T P (V fragments shared across groups) ----
#pragma unroll
    for (int ks = 0; ks < 2; ++ks) {
        lacc[0] = __builtin_amdgcn_mfma_f32_16x16x32_bf16(ones, bp[0][ks], lacc[0], 0, 0, 0);
        lacc[1] = __builtin_amdgcn_mfma_f32_16x16x32_bf16(ones, bp[1][ks], lacc[1], 0, 0, 0);
#pragma unroll
        for (int ct = 0; ct < 4; ++ct) {
            bf16x8 av = *reinterpret_cast<const bf16x8*>(
                &Vc[(ct * 16 + col0) * 64 + ((ks * 4 + quad) ^ (col0 & 7)) * 8]);
            ot[0][ct] = __builtin_amdgcn_mfma_f32_16x16x32_bf16(av, bp[0][ks], ot[0][ct], 0, 0, 0);
            ot[1][ct] = __builtin_amdgcn_mfma_f32_16x16x32_bf16(av, bp[1][ks], ot[1][ct], 0, 0, 0);
        }
    }
}

__device__ __forceinline__ void attn_pass(
    const unsigned short* __restrict__ Qg,
    const unsigned short* __restrict__ Kg,
    const unsigned short* __restrict__ Vtg,
    unsigned short* __restrict__ ctx,
    size_t base, int b, int h, int jj,
    int tid, int w, int quad, int col0,
    unsigned short* K0, unsigned short* K1, unsigned short* K2, unsigned short* K3,
    unsigned short* V0, unsigned short* V1, unsigned short* V2, unsigned short* V3,
    unsigned short* Psw, const bf16x8& ones) {

    const int q0 = jj * 128 + w * 32;     // wave's 32-row base
    const int qlim = q0 + 31;

    // Q fragments (B-operand) for 2 q-groups, held across the k-loop
    bf16x8 bq[2][2];
#pragma unroll
    for (int g = 0; g < 2; ++g)
#pragma unroll
        for (int ks = 0; ks < 2; ++ks)
            bq[g][ks] = *reinterpret_cast<const bf16x8*>(
                Qg + base + (size_t)(q0 + g * 16 + col0) * SHD + ks * 32 + quad * 8);

    f32x4 ot[2][4], lacc[2];
    const f32x4 z = {0.f, 0.f, 0.f, 0.f};
#pragma unroll
    for (int g = 0; g < 2; ++g) {
        lacc[g] = z;
#pragma unroll
        for (int ct = 0; ct < 4; ++ct) ot[g][ct] = z;
    }

    const int srow0 = tid >> 3;                      // 0..31
    const int scs = tid & 7;                         // chunk slot in row
    const int nkt = 2 * jj + 2;                      // even

    // prologue: prior-pass reads of these buffers completed, stage tiles 0,1
    __syncthreads();
    stage_kv(Kg, Vtg, base, 0, srow0, scs, tid, K0, V0);
    if (1 < nkt) stage_kv(Kg, Vtg, base, 1, srow0, scs, tid, K1, V1);

#pragma unroll 1
    for (int kt = 0; kt < nkt; kt += 4) {
        __syncthreads();   // publishes tiles kt, kt+1 (vmcnt drained)
        if (kt + 2 < nkt) stage_kv(Kg, Vtg, base, kt + 2, srow0, scs, tid, K2, V2);
        if (kt + 3 < nkt) stage_kv(Kg, Vtg, base, kt + 3, srow0, scs, tid, K3, V3);
        if (kt * 64 <= qlim)
            attn_tile(K0, V0, kt * 64, q0, quad, col0, bq, ones, Psw, ot, lacc);
        if ((kt + 1) * 64 <= qlim)
            attn_tile(K1, V1, (kt + 1) * 64, q0, quad, col0, bq, ones, Psw, ot, lacc);

        if (kt + 2 >= nkt) break;
        __syncthreads();   // publishes tiles kt+2, kt+3
        if (kt + 4 < nkt) stage_kv(Kg, Vtg, base, kt + 4, srow0, scs, tid, K0, V0);
        if (kt + 5 < nkt) stage_kv(Kg, Vtg, base, kt + 5, srow0, scs, tid, K1, V1);
        if ((kt + 2) * 64 <= qlim)
            attn_tile(K2, V2, (kt + 2) * 64, q0, quad, col0, bq, ones, Psw, ot, lacc);
        if (kt + 3 < nkt && (kt + 3) * 64 <= qlim)
            attn_tile(K3, V3, (kt + 3) * 64, q0, quad, col0, bq, ones, Psw, ot, lacc);
    }

    // ---- epilogue: ctx[b][q][h*64+hd]; O^T col=q, row=hd; l = lacc[.][0] ----
#pragma unroll
    for (int g = 0; g < 2; ++g) {
        float inv = 1.0f / lacc[g][0];
        int q = q0 + g * 16 + col0;
        size_t obase = ((size_t)b * SS + q) * SD + h * SHD;
#pragma unroll
        for (int ct = 0; ct < 4; ++ct) {
            uint2 pk;
            pk.x = pkhi(ot[g][ct][1] * inv, ot[g][ct][0] * inv);
            pk.y = pkhi(ot[g][ct][3] * inv, ot[g][ct][2] * inv);
            *reinterpret_cast<uint2*>(ctx + obase + ct * 16 + quad * 4) = pk;
        }
    }
}

__global__ __launch_bounds__(256) void attn_kernel(
    const unsigned short* __restrict__ Qg,
    const unsigned short* __restrict__ Kg,
    const unsigned short* __restrict__ Vtg,
    unsigned short* __restrict__ ctx) {

    __shared__ __align__(16) unsigned short K0[64 * 64];
    __shared__ __align__(16) unsigned short K1[64 * 64];
    __shared__ __align__(16) unsigned short K2[64 * 64];
    __shared__ __align__(16) unsigned short K3[64 * 64];
    __shared__ __align__(16) unsigned short V0[64 * 64];
    __shared__ __align__(16) unsigned short V1[64 * 64];
    __shared__ __align__(16) unsigned short V2[64 * 64];
    __shared__ __align__(16) unsigned short V3[64 * 64];
    __shared__ __align__(16) unsigned short Ps[4 * 16 * PSTR]; // per-wave

    const int tid = threadIdx.x;
    const int w = tid >> 6;
    const int lane = tid & 63;
    const int quad = lane >> 4;
    const int col0 = lane & 15;
    const int bh = blockIdx.y;
    const int b = bh >> 4;
    const int h = bh & 15;
    const size_t base = (size_t)bh * (SS * SHD);
    unsigned short* Psw = Ps + w * 16 * PSTR;

    bf16x8 ones;
#pragma unroll
    for (int i = 0; i < 8; ++i) ones[i] = (__bf16)1.0f;

    // paired q-tiles jj and 15-jj -> uniform 34 k-tiles per block
    attn_pass(Qg, Kg, Vtg, ctx, base, b, h, blockIdx.x,
              tid, w, quad, col0, K0, K1, K2, K3, V0, V1, V2, V3, Psw, ones);
    attn_pass(Qg, Kg, Vtg, ctx, base, b, h, 15 - blockIdx.x,
              tid, w, quad, col0, K0, K1, K2, K3, V0, V1, V2, V3, Psw, ones);
}

// ---------------- launcher ----------------
// ws layout (bytes):
//  xb    @ 0          16,777,216
//  wqkv  @ 16777216    6,291,456
//  q     @ 23068672   16,777,216
//  k     @ 39845888   16,777,216
//  vt    @ 56623104   16,777,216
//  ctx   @ 73400320   16,777,216
//  wo16  @ 90177536    2,097,152   total 92,274,688
extern "C" void kernel_launch(void* const* d_in, const int* in_sizes, int n_in,
                              void* d_out, int out_size, void* d_ws, size_t ws_size,
                              hipStream_t stream) {
    const float* x  = (const float*)d_in[0];
    const float* wq = (const float*)d_in[1];
    const float* wk = (const float*)d_in[2];
    const float* wv = (const float*)d_in[3];
    const float* wo = (const float*)d_in[4];
    const float* wb = (const float*)d_in[5];
    float* out = (float*)d_out;

    char* ws = (char*)d_ws;
    unsigned short* xb   = (unsigned short*)(ws + 0);
    unsigned short* wqkv = (unsigned short*)(ws + 16777216);
    unsigned short* q    = (unsigned short*)(ws + 23068672);
    unsigned short* k    = (unsigned short*)(ws + 39845888);
    unsigned short* vt   = (unsigned short*)(ws + 56623104);
    unsigned short* ctx  = (unsigned short*)(ws + 73400320);
    unsigned short* wo16 = (unsigned short*)(ws + 90177536);

    // fused casts: 3145728 float4 units / 256 = 12288 blocks
    cast_all<<<12288, 256, 0, stream>>>(x, wq, wk, wv, wo, xb, wqkv, wo16);

    // QKV projection: M=8192, N=3072
    gemm_qkv<<<dim3(3 * SD / 128, SM / 128), 256, 0, stream>>>(xb, wqkv, q, k, vt);

    // attention: grid (8 pair-tiles, B*H)
    attn_kernel<<<dim3(8, SB * SH), 256, 0, stream>>>(q, k, vt, ctx);

    // output projection: M=8192, N=1024, +bias, fp32 out
    gemm_out<<<dim3(SD / 128, SM / 128), 256, 0, stream>>>(ctx, wo16, wb, out);
}